// Round 1
// baseline (303.763 us; speedup 1.0000x reference)
//
#include <hip/hip_runtime.h>
#include <float.h>
#include <math.h>

// Problem constants (S=4096 tokens, E=64 experts, CAP=128)
#define SS 4096
#define EE 64
#define CAPC 128
#define SEC (4096LL * 64 * 128)   // 33,554,432 elements per [S,E,C] tensor

// ---------------------------------------------------------------------------
// Kernel Z: zero the entire output buffer (268 MB) with float4 stores,
// and zero the 64-float gate-sum accumulator in workspace.
// ---------------------------------------------------------------------------
__global__ __launch_bounds__(256) void zero_out_kernel(float4* __restrict__ out4,
                                                       long n4,
                                                       float* __restrict__ tail,
                                                       int ntail,
                                                       float* __restrict__ gate_sums) {
    long i = (long)blockIdx.x * blockDim.x + threadIdx.x;
    long stride = (long)gridDim.x * blockDim.x;
    float4 z = make_float4(0.f, 0.f, 0.f, 0.f);
    for (; i < n4; i += stride) out4[i] = z;
    if (blockIdx.x == 0) {
        if (threadIdx.x < 64) gate_sums[threadIdx.x] = 0.f;
        if ((int)threadIdx.x < ntail) tail[threadIdx.x] = 0.f;
    }
}

// ---------------------------------------------------------------------------
// Kernel 1: per-token softmax + top-1 / top-2 expert selection.
// One wave (64 lanes) per token; lane = expert index.
// ---------------------------------------------------------------------------
__global__ __launch_bounds__(256) void gate_kernel(const float* __restrict__ logits,
                                                   const float* __restrict__ noise,
                                                   int* __restrict__ idx1s,
                                                   int* __restrict__ idx2s,
                                                   float* __restrict__ g1raw,
                                                   float* __restrict__ g2raw,
                                                   float* __restrict__ gate_sums) {
    const int tid  = threadIdx.x;
    const int wave = tid >> 6;
    const int lane = tid & 63;
    const int s    = blockIdx.x * 4 + wave;

    const float l = logits[s * EE + lane];
    const float n = noise[s * EE + lane];

    // argmax over logits with first-index tie-break (butterfly, all lanes get result)
    float v = l; int bi = lane;
    #pragma unroll
    for (int off = 32; off; off >>= 1) {
        float v2 = __shfl_xor(v, off, 64);
        int   i2 = __shfl_xor(bi, off, 64);
        if (v2 > v || (v2 == v && i2 < bi)) { v = v2; bi = i2; }
    }
    const int idx1 = bi;
    const float m = v;   // max logit

    // softmax
    float e = expf(l - m);
    float sum = e;
    #pragma unroll
    for (int off = 32; off; off >>= 1) sum += __shfl_xor(sum, off, 64);
    const float gate = e / sum;
    const float g1 = __shfl(gate, idx1, 64);

    // top-2 from logits+noise with top-1 masked to -FLT_MAX (== finfo(f32).min)
    float lw = (lane == idx1) ? -FLT_MAX : (l + n);
    float v2v = lw; int bi2 = lane;
    #pragma unroll
    for (int off = 32; off; off >>= 1) {
        float v2 = __shfl_xor(v2v, off, 64);
        int   i2 = __shfl_xor(bi2, off, 64);
        if (v2 > v2v || (v2 == v2v && i2 < bi2)) { v2v = v2; bi2 = i2; }
    }
    const int idx2 = bi2;
    const float g2 = __shfl(gate, idx2, 64);

    if (lane == 0) {
        idx1s[s] = idx1;
        idx2s[s] = idx2;
        g1raw[s] = g1;
        g2raw[s] = g2;
    }

    // accumulate per-expert gate sums (for l_aux 'me' term)
    __shared__ float sg[256];
    sg[tid] = gate;
    __syncthreads();
    if (tid < 64) {
        float t = sg[tid] + sg[tid + 64] + sg[tid + 128] + sg[tid + 192];
        atomicAdd(&gate_sums[tid], t);
    }
}

// ---------------------------------------------------------------------------
// Kernel 2a: per-chunk (64 tokens) within-chunk ranks and per-expert counts.
// 64 blocks (one per chunk) x 64 threads (thread = token-in-chunk AND expert).
// ---------------------------------------------------------------------------
__global__ __launch_bounds__(64) void chunk_rank_kernel(const int* __restrict__ idx1s,
                                                        const int* __restrict__ idx2s,
                                                        int* __restrict__ wrank1,
                                                        int* __restrict__ wrank2,
                                                        int* __restrict__ cnt1,
                                                        int* __restrict__ cnt2) {
    __shared__ int li1[64], li2[64];
    const int t = threadIdx.x;
    const int chunk = blockIdx.x;
    const int s = chunk * 64 + t;
    li1[t] = idx1s[s];
    li2[t] = idx2s[s];
    __syncthreads();
    const int my1 = li1[t], my2 = li2[t];
    int r1 = 0, r2 = 0, c1 = 0, c2 = 0;
    #pragma unroll 8
    for (int j = 0; j < 64; ++j) {
        const int a = li1[j], b = li2[j];
        r1 += (int)((j < t) & (a == my1));
        r2 += (int)((j < t) & (b == my2));
        c1 += (int)(a == t);
        c2 += (int)(b == t);
    }
    wrank1[s] = r1;
    wrank2[s] = r2;
    cnt1[chunk * 64 + t] = c1;
    cnt2[chunk * 64 + t] = c2;
}

// ---------------------------------------------------------------------------
// Kernel 2b: exclusive prefix over chunks per expert -> offsets + totals.
// Also computes l_aux = (E/S^2) * sum_e gate_sum_e * count1_e and writes d_out[0].
// 1 block x 64 threads (thread = expert).
// ---------------------------------------------------------------------------
__global__ __launch_bounds__(64) void scan_kernel(const int* __restrict__ cnt1,
                                                  const int* __restrict__ cnt2,
                                                  int* __restrict__ off1,
                                                  int* __restrict__ off2,
                                                  int* __restrict__ count1,
                                                  const float* __restrict__ gate_sums,
                                                  float* __restrict__ d_out) {
    const int e = threadIdx.x;
    int o1 = 0, o2 = 0;
    #pragma unroll 8
    for (int c = 0; c < 64; ++c) {
        off1[c * 64 + e] = o1; o1 += cnt1[c * 64 + e];
        off2[c * 64 + e] = o2; o2 += cnt2[c * 64 + e];
    }
    count1[e] = o1;

    float prod = gate_sums[e] * (float)o1;
    #pragma unroll
    for (int off = 32; off; off >>= 1) prod += __shfl_xor(prod, off, 64);
    if (e == 0) {
        // l_aux = mean(me*ce) * E^2 = (E / S^2) * sum_e gs_e * cnt_e
        d_out[0] = prod * (float)EE / ((float)SS * (float)SS);
    }
}

// ---------------------------------------------------------------------------
// Kernel 3: scatter nonzero combine weights + dispatch mask.
// One thread per token.
// ---------------------------------------------------------------------------
__global__ __launch_bounds__(256) void scatter_kernel(const int* __restrict__ idx1s,
                                                      const int* __restrict__ idx2s,
                                                      const int* __restrict__ wrank1,
                                                      const int* __restrict__ wrank2,
                                                      const int* __restrict__ off1,
                                                      const int* __restrict__ off2,
                                                      const int* __restrict__ count1,
                                                      const float* __restrict__ g1raw,
                                                      const float* __restrict__ g2raw,
                                                      float* __restrict__ d_out) {
    const int s = blockIdx.x * 256 + threadIdx.x;
    if (s >= SS) return;
    const int i1 = idx1s[s];
    const int i2 = idx2s[s];
    const int chunk = s >> 6;
    const int loc1 = wrank1[s] + off1[chunk * 64 + i1];
    const int loc2 = wrank2[s] + off2[chunk * 64 + i2] + count1[i2];
    float g1 = g1raw[s];
    float g2 = g2raw[s];
    const bool k1 = loc1 < CAPC;
    const bool k2 = loc2 < CAPC;
    g1 = k1 ? g1 : 0.f;
    g2 = k2 ? g2 : 0.f;
    const float denom = fmaxf(g1 + g2, 1.1920929e-07f);  // finfo(f32).eps
    g1 /= denom;
    g2 /= denom;

    float* combine = d_out + 1;
    float* mask    = d_out + 1 + SEC;
    const long base = (long)s * (EE * CAPC);
    if (k1 && g1 != 0.f) {
        const long p = base + (long)i1 * CAPC + loc1;
        combine[p] = g1;
        mask[p]    = 1.f;
    }
    if (k2 && g2 != 0.f) {
        const long p = base + (long)i2 * CAPC + loc2;
        combine[p] = g2;
        mask[p]    = 1.f;
    }
}

// ---------------------------------------------------------------------------
// Launch
// ---------------------------------------------------------------------------
extern "C" void kernel_launch(void* const* d_in, const int* in_sizes, int n_in,
                              void* d_out, int out_size, void* d_ws, size_t ws_size,
                              hipStream_t stream) {
    const float* logits = (const float*)d_in[0];
    const float* noise  = (const float*)d_in[1];
    float* out = (float*)d_out;

    char* ws = (char*)d_ws;
    int*   idx1s     = (int*)  (ws + 0);
    int*   idx2s     = (int*)  (ws + 16384);
    int*   wrank1    = (int*)  (ws + 32768);
    int*   wrank2    = (int*)  (ws + 49152);
    float* g1raw     = (float*)(ws + 65536);
    float* g2raw     = (float*)(ws + 81920);
    int*   cnt1      = (int*)  (ws + 98304);
    int*   cnt2      = (int*)  (ws + 114688);
    int*   off1      = (int*)  (ws + 131072);
    int*   off2      = (int*)  (ws + 147456);
    int*   count1    = (int*)  (ws + 163840);
    float* gate_sums = (float*)(ws + 164096);

    const long n4 = (long)out_size / 4;          // float4 count
    const int ntail = (int)((long)out_size - n4 * 4);

    zero_out_kernel<<<4096, 256, 0, stream>>>((float4*)out, n4, out + n4 * 4, ntail, gate_sums);
    gate_kernel<<<SS / 4, 256, 0, stream>>>(logits, noise, idx1s, idx2s, g1raw, g2raw, gate_sums);
    chunk_rank_kernel<<<64, 64, 0, stream>>>(idx1s, idx2s, wrank1, wrank2, cnt1, cnt2);
    scan_kernel<<<1, 64, 0, stream>>>(cnt1, cnt2, off1, off2, count1, gate_sums, out);
    scatter_kernel<<<SS / 256, 256, 0, stream>>>(idx1s, idx2s, wrank1, wrank2,
                                                 off1, off2, count1, g1raw, g2raw, out);
}

// Round 2
// 284.949 us; speedup vs baseline: 1.0660x; 1.0660x over previous
//
#include <hip/hip_runtime.h>
#include <float.h>
#include <math.h>

// Problem constants (S=4096 tokens, E=64 experts, CAP=128)
#define SS 4096
#define EE 64
#define CAPC 128
#define ROW (EE * CAPC)           // 8192 floats per token per tensor
#define SEC (4096LL * 64 * 128)   // 33,554,432 elements per [S,E,C] tensor

// ---------------------------------------------------------------------------
// Kernel 1: per-token softmax + top-1 / top-2 expert selection.
// One wave (64 lanes) per token; lane = expert index. 4 tokens per block.
// Per-block per-expert gate partial sums written (no atomics).
// ---------------------------------------------------------------------------
__global__ __launch_bounds__(256) void gate_kernel(const float* __restrict__ logits,
                                                   const float* __restrict__ noise,
                                                   int* __restrict__ idx1s,
                                                   int* __restrict__ idx2s,
                                                   float* __restrict__ g1raw,
                                                   float* __restrict__ g2raw,
                                                   float* __restrict__ partial) {
    const int tid  = threadIdx.x;
    const int wave = tid >> 6;
    const int lane = tid & 63;
    const int s    = blockIdx.x * 4 + wave;

    const float l = logits[s * EE + lane];
    const float n = noise[s * EE + lane];

    // argmax over logits, first-index tie-break (butterfly, all lanes agree)
    float v = l; int bi = lane;
    #pragma unroll
    for (int off = 32; off; off >>= 1) {
        float v2 = __shfl_xor(v, off, 64);
        int   i2 = __shfl_xor(bi, off, 64);
        if (v2 > v || (v2 == v && i2 < bi)) { v = v2; bi = i2; }
    }
    const int idx1 = bi;
    const float m = v;

    // softmax
    float e = expf(l - m);
    float sum = e;
    #pragma unroll
    for (int off = 32; off; off >>= 1) sum += __shfl_xor(sum, off, 64);
    const float gate = e / sum;
    const float g1 = __shfl(gate, idx1, 64);

    // top-2 from logits+noise with top-1 masked to -FLT_MAX
    float lw = (lane == idx1) ? -FLT_MAX : (l + n);
    float v2v = lw; int bi2 = lane;
    #pragma unroll
    for (int off = 32; off; off >>= 1) {
        float v2 = __shfl_xor(v2v, off, 64);
        int   i2 = __shfl_xor(bi2, off, 64);
        if (v2 > v2v || (v2 == v2v && i2 < bi2)) { v2v = v2; bi2 = i2; }
    }
    const int idx2 = bi2;
    const float g2 = __shfl(gate, idx2, 64);

    if (lane == 0) {
        idx1s[s] = idx1;
        idx2s[s] = idx2;
        g1raw[s] = g1;
        g2raw[s] = g2;
    }

    // per-block per-expert gate sums (for l_aux 'me' term), no atomics
    __shared__ float sg[256];
    sg[tid] = gate;
    __syncthreads();
    if (tid < 64) {
        partial[blockIdx.x * 64 + tid] =
            sg[tid] + sg[tid + 64] + sg[tid + 128] + sg[tid + 192];
    }
}

// ---------------------------------------------------------------------------
// Kernel 2: per-chunk (64 tokens) within-chunk ranks and per-expert counts,
// plus level-1 reduction of the gate partials (1024 -> 64 per expert).
// 64 blocks x 64 threads (thread = token-in-chunk AND expert).
// ---------------------------------------------------------------------------
__global__ __launch_bounds__(64) void rank_kernel(const int* __restrict__ idx1s,
                                                  const int* __restrict__ idx2s,
                                                  int* __restrict__ wrank1,
                                                  int* __restrict__ wrank2,
                                                  int* __restrict__ cnt1,
                                                  int* __restrict__ cnt2,
                                                  const float* __restrict__ partial,
                                                  float* __restrict__ partial2) {
    __shared__ int li1[64], li2[64];
    const int t = threadIdx.x;
    const int chunk = blockIdx.x;
    const int s = chunk * 64 + t;
    li1[t] = idx1s[s];
    li2[t] = idx2s[s];

    // reduce 16 gate-partial blocks for expert t
    float acc = 0.f;
    #pragma unroll
    for (int k = 0; k < 16; ++k) acc += partial[(chunk * 16 + k) * 64 + t];
    partial2[chunk * 64 + t] = acc;

    __syncthreads();
    const int my1 = li1[t], my2 = li2[t];
    int r1 = 0, r2 = 0, c1 = 0, c2 = 0;
    #pragma unroll 8
    for (int j = 0; j < 64; ++j) {
        const int a = li1[j], b = li2[j];
        r1 += (int)((j < t) & (a == my1));
        r2 += (int)((j < t) & (b == my2));
        c1 += (int)(a == t);
        c2 += (int)(b == t);
    }
    wrank1[s] = r1;
    wrank2[s] = r2;
    cnt1[chunk * 64 + t] = c1;
    cnt2[chunk * 64 + t] = c2;
}

// ---------------------------------------------------------------------------
// Kernel 3: exclusive prefix over chunks per expert -> offsets + totals.
// Also finishes l_aux = (E/S^2) * sum_e gate_sum_e * count1_e into ws.
// 1 block x 64 threads (thread = expert).
// ---------------------------------------------------------------------------
__global__ __launch_bounds__(64) void scan_kernel(const int* __restrict__ cnt1,
                                                  const int* __restrict__ cnt2,
                                                  int* __restrict__ off1,
                                                  int* __restrict__ off2,
                                                  int* __restrict__ count1,
                                                  const float* __restrict__ partial2,
                                                  float* __restrict__ laux_ws) {
    const int e = threadIdx.x;
    int o1 = 0, o2 = 0;
    #pragma unroll 8
    for (int c = 0; c < 64; ++c) {
        off1[c * 64 + e] = o1; o1 += cnt1[c * 64 + e];
        off2[c * 64 + e] = o2; o2 += cnt2[c * 64 + e];
    }
    count1[e] = o1;

    float gs = 0.f;
    #pragma unroll 8
    for (int c = 0; c < 64; ++c) gs += partial2[c * 64 + e];

    float prod = gs * (float)o1;
    #pragma unroll
    for (int off = 32; off; off >>= 1) prod += __shfl_xor(prod, off, 64);
    if (e == 0) {
        // l_aux = mean(me*ce) * E^2 = (E / S^2) * sum_e gs_e * cnt_e
        laux_ws[0] = prod * (float)EE / ((float)SS * (float)SS);
    }
}

// ---------------------------------------------------------------------------
// Kernel 4: fused zero + scatter. Each block owns 4 tokens and zeroes exactly
// those tokens' rows in combine_weights and dispatch_mask, then writes the
// <=2 nonzero entries per token. Rows start at out + 1 + s*ROW (offset = 1
// mod 4), so zero as: 3 head scalars + 8191 float4 + 1 tail scalar per tensor.
// Block 0 also writes l_aux to out[0].
// ---------------------------------------------------------------------------
__global__ __launch_bounds__(256) void zero_scatter_kernel(const int* __restrict__ idx1s,
                                                           const int* __restrict__ idx2s,
                                                           const int* __restrict__ wrank1,
                                                           const int* __restrict__ wrank2,
                                                           const int* __restrict__ off1,
                                                           const int* __restrict__ off2,
                                                           const int* __restrict__ count1,
                                                           const float* __restrict__ g1raw,
                                                           const float* __restrict__ g2raw,
                                                           const float* __restrict__ laux_ws,
                                                           float* __restrict__ out) {
    const int tid = threadIdx.x;
    const int t0  = blockIdx.x * 4;
    const long cb = (long)t0 * ROW;   // base (in floats) of this block's 4 rows

    // --- prefetch scatter operands (overlaps with the zero stores below) ---
    int i1 = 0, i2 = 0, loc1 = 0, loc2 = 0;
    float g1 = 0.f, g2 = 0.f;
    bool k1 = false, k2 = false;
    if (tid < 4) {
        const int s = t0 + tid;
        i1 = idx1s[s];
        i2 = idx2s[s];
        const int chunk = s >> 6;
        loc1 = wrank1[s] + off1[chunk * 64 + i1];
        loc2 = wrank2[s] + off2[chunk * 64 + i2] + count1[i2];
        g1 = g1raw[s];
        g2 = g2raw[s];
        k1 = loc1 < CAPC;
        k2 = loc2 < CAPC;
        g1 = k1 ? g1 : 0.f;
        g2 = k2 ? g2 : 0.f;
        const float denom = fmaxf(g1 + g2, 1.1920929e-07f);  // finfo(f32).eps
        g1 /= denom;
        g2 /= denom;
    }

    // --- zero the 4 combine rows and 4 mask rows owned by this block ---
    const float4 z = make_float4(0.f, 0.f, 0.f, 0.f);
    float4* p4 = (float4*)(out + cb + 4);          // combine, 8191 float4
    float4* q4 = (float4*)(out + SEC + cb + 4);    // mask,    8191 float4
    #pragma unroll
    for (int i = tid; i < 8191; i += 256) p4[i] = z;
    #pragma unroll
    for (int i = tid; i < 8191; i += 256) q4[i] = z;
    if (tid < 3) {
        out[cb + 1 + tid] = 0.f;
        out[SEC + cb + 1 + tid] = 0.f;
    } else if (tid == 3) {
        out[cb + 4L * ROW] = 0.f;          // tail scalar of 4th combine row
        out[SEC + cb + 4L * ROW] = 0.f;    // tail scalar of 4th mask row
    }
    __syncthreads();

    // --- scatter ---
    if (tid < 4) {
        const int s = t0 + tid;
        float* combine = out + 1;
        float* mask    = out + 1 + SEC;
        const long base = (long)s * ROW;
        if (k1 && g1 != 0.f) {
            const long p = base + (long)i1 * CAPC + loc1;
            combine[p] = g1;
            mask[p]    = 1.f;
        }
        if (k2 && g2 != 0.f) {
            const long p = base + (long)i2 * CAPC + loc2;
            combine[p] = g2;
            mask[p]    = 1.f;
        }
    }
    if (tid == 4 && blockIdx.x == 0) {
        out[0] = laux_ws[0];
    }
}

// ---------------------------------------------------------------------------
// Launch
// ---------------------------------------------------------------------------
extern "C" void kernel_launch(void* const* d_in, const int* in_sizes, int n_in,
                              void* d_out, int out_size, void* d_ws, size_t ws_size,
                              hipStream_t stream) {
    const float* logits = (const float*)d_in[0];
    const float* noise  = (const float*)d_in[1];
    float* out = (float*)d_out;

    char* ws = (char*)d_ws;
    int*   idx1s    = (int*)  (ws + 0);
    int*   idx2s    = (int*)  (ws + 16384);
    int*   wrank1   = (int*)  (ws + 32768);
    int*   wrank2   = (int*)  (ws + 49152);
    float* g1raw    = (float*)(ws + 65536);
    float* g2raw    = (float*)(ws + 81920);
    int*   cnt1     = (int*)  (ws + 98304);
    int*   cnt2     = (int*)  (ws + 114688);
    int*   off1     = (int*)  (ws + 131072);
    int*   off2     = (int*)  (ws + 147456);
    int*   count1   = (int*)  (ws + 163840);
    float* laux_ws  = (float*)(ws + 164352);
    float* partial  = (float*)(ws + 196608);   // 1024 x 64 floats (256 KB)
    float* partial2 = (float*)(ws + 458752);   // 64 x 64 floats (16 KB)

    gate_kernel<<<SS / 4, 256, 0, stream>>>(logits, noise, idx1s, idx2s, g1raw, g2raw, partial);
    rank_kernel<<<64, 64, 0, stream>>>(idx1s, idx2s, wrank1, wrank2, cnt1, cnt2, partial, partial2);
    scan_kernel<<<1, 64, 0, stream>>>(cnt1, cnt2, off1, off2, count1, partial2, laux_ws);
    zero_scatter_kernel<<<SS / 4, 256, 0, stream>>>(idx1s, idx2s, wrank1, wrank2,
                                                    off1, off2, count1, g1raw, g2raw,
                                                    laux_ws, out);
}